// Round 7
// baseline (89.356 us; speedup 1.0000x reference)
//
#include <hip/hip_runtime.h>

#define NC 2048
#define D 64
#define H 32

// ---------------- K1: segment bounds (owner sorted ascending) -------------
__global__ void bounds_kernel(const int* __restrict__ owner,
                              int* __restrict__ bounds, int n) {
    int i = blockIdx.x * blockDim.x + threadIdx.x;
    if (i >= n) return;
    int o  = owner[i];
    int op = (i == 0) ? -1 : owner[i - 1];
    for (int g = op + 1; g <= o; ++g) bounds[g] = i;
    if (i == n - 1)
        for (int g = o + 1; g <= NC; ++g) bounds[g] = n;
}

// ---------------- K2: fully-fused per-crystal kernel ----------------------
// Block = 1 crystal, 256 threads = 4 waves; wave wv owns a CONTIGUOUS slice.
// Lane = (dg = lane>>5, h = lane&31):
//   wkr[32] = Wk[dg*32 .. +31][h]   (constant over atoms, registers)
//   acc[32] = out[g][dg*32+j][h]
// Per atom: 8 float4 fea loads -> 4 independent logit chains -> shfl_xor(32)
// cross-half reduce -> exp -> outer-product FMAs. Per-lane running sum of p
// IS the softmax denominator (no reductions). No max subtraction (softmax
// shift-invariance; |w| <~ 6, f32-safe; absmax 0.0078 vs thr 0.0478 R2-R5).
//
// R4/R5 lesson: float4 arrays accessed through a pointer (lambda param) went
// addressable -> SROA failed -> scratch spill (VGPR 84-88, WRITE_SIZE +6.5MB).
// Double buffer is NAMED registers passed explicitly to macros (no pasting,
// no arrays, nothing addressable).
__global__ __launch_bounds__(256, 3) void crystal_kernel(
    const float* __restrict__ atom_feas,
    const float* __restrict__ Wk,
    const float* __restrict__ bk,
    const int* __restrict__ bounds,
    float* __restrict__ out)
{
    __shared__ float part[3][64][33];   // waves 1..3 partials, pad 33: 25.3 KB

    const int g    = blockIdx.x;
    const int tid  = threadIdx.x;
    const int lane = tid & 63;
    const int wv   = tid >> 6;
    const int h    = lane & 31;
    const int dg   = lane >> 5;
    const int d0   = dg * 32;

    float wkr[32];
    #pragma unroll
    for (int j = 0; j < 32; ++j) wkr[j] = Wk[(d0 + j) * H + h];
    const float bkv = bk[h];

    const int s   = bounds[g];
    const int e   = bounds[g + 1];
    const int nA  = e - s;
    const int per = (nA + 3) >> 2;
    int a         = s + wv * per;
    const int ae  = min(a + per, e);

    float acc[32];
    #pragma unroll
    for (int j = 0; j < 32; ++j) acc[j] = 0.f;
    float es = 0.f;

    float4 A0, A1, A2, A3, A4, A5, A6, A7;
    float4 B0, B1, B2, B3, B4, B5, B6, B7;

#define LOAD8(R0, R1, R2, R3, R4, R5, R6, R7, aa)                              \
    {                                                                          \
        const float4* fp = (const float4*)(atom_feas + (size_t)(aa) * D + d0); \
        R0 = fp[0]; R1 = fp[1]; R2 = fp[2]; R3 = fp[3];                        \
        R4 = fp[4]; R5 = fp[5]; R6 = fp[6]; R7 = fp[7];                        \
    }

#define COMPUTE(R0, R1, R2, R3, R4, R5, R6, R7)                                \
    {                                                                          \
        float q0 = R0.x * wkr[0]  + R0.y * wkr[1]                              \
                 + R0.z * wkr[2]  + R0.w * wkr[3]                              \
                 + R1.x * wkr[4]  + R1.y * wkr[5]                              \
                 + R1.z * wkr[6]  + R1.w * wkr[7];                             \
        float q1 = R2.x * wkr[8]  + R2.y * wkr[9]                              \
                 + R2.z * wkr[10] + R2.w * wkr[11]                             \
                 + R3.x * wkr[12] + R3.y * wkr[13]                             \
                 + R3.z * wkr[14] + R3.w * wkr[15];                            \
        float q2 = R4.x * wkr[16] + R4.y * wkr[17]                             \
                 + R4.z * wkr[18] + R4.w * wkr[19]                             \
                 + R5.x * wkr[20] + R5.y * wkr[21]                             \
                 + R5.z * wkr[22] + R5.w * wkr[23];                            \
        float q3 = R6.x * wkr[24] + R6.y * wkr[25]                             \
                 + R6.z * wkr[26] + R6.w * wkr[27]                             \
                 + R7.x * wkr[28] + R7.y * wkr[29]                             \
                 + R7.z * wkr[30] + R7.w * wkr[31];                            \
        float wlog = (q0 + q1) + (q2 + q3);                                    \
        wlog += __shfl_xor(wlog, 32, 64);                                      \
        const float p = __expf(wlog + bkv);                                    \
        es += p;                                                               \
        acc[0]  += R0.x * p; acc[1]  += R0.y * p;                              \
        acc[2]  += R0.z * p; acc[3]  += R0.w * p;                              \
        acc[4]  += R1.x * p; acc[5]  += R1.y * p;                              \
        acc[6]  += R1.z * p; acc[7]  += R1.w * p;                              \
        acc[8]  += R2.x * p; acc[9]  += R2.y * p;                              \
        acc[10] += R2.z * p; acc[11] += R2.w * p;                              \
        acc[12] += R3.x * p; acc[13] += R3.y * p;                              \
        acc[14] += R3.z * p; acc[15] += R3.w * p;                              \
        acc[16] += R4.x * p; acc[17] += R4.y * p;                              \
        acc[18] += R4.z * p; acc[19] += R4.w * p;                              \
        acc[20] += R5.x * p; acc[21] += R5.y * p;                              \
        acc[22] += R5.z * p; acc[23] += R5.w * p;                              \
        acc[24] += R6.x * p; acc[25] += R6.y * p;                              \
        acc[26] += R6.z * p; acc[27] += R6.w * p;                              \
        acc[28] += R7.x * p; acc[29] += R7.y * p;                              \
        acc[30] += R7.z * p; acc[31] += R7.w * p;                              \
    }

    if (a < ae) {
        LOAD8(A0, A1, A2, A3, A4, A5, A6, A7, a);
        for (;;) {
            const int n1 = a + 1;
            if (n1 >= ae) { COMPUTE(A0, A1, A2, A3, A4, A5, A6, A7); break; }
            LOAD8(B0, B1, B2, B3, B4, B5, B6, B7, n1);
            COMPUTE(A0, A1, A2, A3, A4, A5, A6, A7);
            const int n2 = n1 + 1;
            if (n2 >= ae) { COMPUTE(B0, B1, B2, B3, B4, B5, B6, B7); break; }
            LOAD8(A0, A1, A2, A3, A4, A5, A6, A7, n2);
            COMPUTE(B0, B1, B2, B3, B4, B5, B6, B7);
            a = n2;
        }
    }
#undef LOAD8
#undef COMPUTE

    // ---- cross-wave combine (once per block)
    if (wv > 0) {
        #pragma unroll
        for (int j = 0; j < 32; ++j) part[wv - 1][lane][j] = acc[j];
        part[wv - 1][lane][32] = es;
    }
    __syncthreads();
    if (wv == 0) {
        #pragma unroll
        for (int j = 0; j < 32; ++j)
            acc[j] += part[0][lane][j] + part[1][lane][j] + part[2][lane][j];
        es += part[0][lane][32] + part[1][lane][32] + part[2][lane][32];
        const float inv = (es > 0.f) ? 1.0f / es : 0.f;
        float* og = out + (size_t)g * (D * H);
        #pragma unroll
        for (int j = 0; j < 32; ++j)
            og[(d0 + j) * H + h] = acc[j] * inv;   // 2x128B per instr, coalesced
    }
}

// ---------------- Fallback (ws too small): known-good fused kernel --------
#define CHUNK 64
__global__ __launch_bounds__(256) void fused_kernel(
    const float* __restrict__ atom_feas,
    const float* __restrict__ Wk,
    const float* __restrict__ bk,
    const int* __restrict__ owner,
    float* __restrict__ out,
    int n_atoms)
{
    __shared__ float fea_lds[CHUNK * D];
    __shared__ float w_lds[CHUNK * H];
    __shared__ float wk_lds[D * H];
    __shared__ float bk_lds[H];

    const int g   = blockIdx.x;
    const int tid = threadIdx.x;
    const int h   = tid & 31;
    const int grp = tid >> 5;

    for (int i = tid; i < D * H; i += 256) wk_lds[i] = Wk[i];
    if (tid < H) bk_lds[tid] = bk[tid];

    int lo = 0, hi = n_atoms;
    while (lo < hi) { int mid = (lo + hi) >> 1; if (owner[mid] < g) lo = mid + 1; else hi = mid; }
    const int seg_start = lo;
    hi = n_atoms;
    while (lo < hi) { int mid = (lo + hi) >> 1; if (owner[mid] < g + 1) lo = mid + 1; else hi = mid; }
    const int seg_end = lo;

    float acc[8];
    #pragma unroll
    for (int j = 0; j < 8; ++j) acc[j] = 0.f;
    float ps = 0.f;

    __syncthreads();

    for (int base = seg_start; base < seg_end; base += CHUNK) {
        const int na = min(CHUNK, seg_end - base);
        {
            const int nf4 = na * (D / 4);
            const float4* src = (const float4*)(atom_feas + (size_t)base * D);
            float4* dst = (float4*)fea_lds;
            for (int i = tid; i < nf4; i += 256) dst[i] = src[i];
        }
        __syncthreads();

        for (int pi = tid; pi < na * H; pi += 256) {
            const int aa = pi >> 5;
            const int hh = pi & 31;
            const float* fr = fea_lds + aa * D;
            float wvl = bk_lds[hh];
            #pragma unroll
            for (int k = 0; k < D; k += 4) {
                float4 f = *(const float4*)(fr + k);
                wvl += f.x * wk_lds[(k + 0) * H + hh];
                wvl += f.y * wk_lds[(k + 1) * H + hh];
                wvl += f.z * wk_lds[(k + 2) * H + hh];
                wvl += f.w * wk_lds[(k + 3) * H + hh];
            }
            w_lds[pi] = __expf(wvl);
        }
        __syncthreads();

        for (int aa = 0; aa < na; ++aa) {
            const float p = w_lds[aa * H + h];
            ps += p;
            const float* f = fea_lds + aa * D + grp * 8;
            #pragma unroll
            for (int j = 0; j < 8; ++j) acc[j] += f[j] * p;
        }
        __syncthreads();
    }

    const float inv = (ps > 0.f) ? 1.0f / ps : 0.f;
    float* og = out + (size_t)g * (D * H);
    #pragma unroll
    for (int j = 0; j < 8; ++j) og[(grp * 8 + j) * H + h] = acc[j] * inv;
}

extern "C" void kernel_launch(void* const* d_in, const int* in_sizes, int n_in,
                              void* d_out, int out_size, void* d_ws, size_t ws_size,
                              hipStream_t stream) {
    const float* atom_feas = (const float*)d_in[0];
    const float* Wk        = (const float*)d_in[1];
    const float* bk        = (const float*)d_in[2];
    // d_in[3] = atomic_numbers (unused by the reference)
    const int*   owner     = (const int*)d_in[4];
    const int n_atoms = in_sizes[4];
    float* out = (float*)d_out;

    if (ws_size >= (NC + 1) * sizeof(int)) {
        int* bounds = (int*)d_ws;
        bounds_kernel<<<(n_atoms + 255) / 256, 256, 0, stream>>>(owner, bounds, n_atoms);
        crystal_kernel<<<NC, 256, 0, stream>>>(atom_feas, Wk, bk, bounds, out);
    } else {
        fused_kernel<<<NC, 256, 0, stream>>>(atom_feas, Wk, bk, owner, out, n_atoms);
    }
}

// Round 8
// 88.553 us; speedup vs baseline: 1.0091x; 1.0091x over previous
//
#include <hip/hip_runtime.h>

#define NC 2048
#define D 64
#define H 32

// ---------------- K1: segment bounds (owner sorted ascending) -------------
__global__ void bounds_kernel(const int* __restrict__ owner,
                              int* __restrict__ bounds, int n) {
    int i = blockIdx.x * blockDim.x + threadIdx.x;
    if (i >= n) return;
    int o  = owner[i];
    int op = (i == 0) ? -1 : owner[i - 1];
    for (int g = op + 1; g <= o; ++g) bounds[g] = i;
    if (i == n - 1)
        for (int g = o + 1; g <= NC; ++g) bounds[g] = n;
}

// ---------------- K2: fully-fused per-crystal kernel ----------------------
// Block = 1 crystal, 256 threads = 4 waves; wave wv owns a CONTIGUOUS slice.
// Lane = (dg = lane>>5, h = lane&31):
//   wkr[32] = Wk[dg*32 .. +31][h]   (constant over atoms, registers)
//   acc[32] = out[g][dg*32+j][h]
// Per atom: 8 float4 fea loads -> 4 independent logit chains -> shfl_xor(32)
// cross-half reduce -> exp -> outer-product FMAs. Per-lane running sum of p
// IS the softmax denominator (no reductions). No max subtraction (softmax
// shift-invariance; |w| <~ 6, f32-safe; absmax 0.0078 vs thr 0.0478 R2-R7).
//
// R4-R7 lesson: the allocator targets the LDS-IMPLIED occupancy (25.3KB LDS
// -> 6 blocks/CU -> 6 waves/EU -> cap 512/6 = 85 VGPR) and SPILLS ~60 floats
// per lane to hit it; __launch_bounds__'s 2nd arg is only a floor, not a
// target. amdgpu_waves_per_eu(3,3) pins the target: cap 512/3 = 170 VGPR,
// demand ~150 -> no spill.
__global__ __launch_bounds__(256)
__attribute__((amdgpu_waves_per_eu(3, 3)))
void crystal_kernel(
    const float* __restrict__ atom_feas,
    const float* __restrict__ Wk,
    const float* __restrict__ bk,
    const int* __restrict__ bounds,
    float* __restrict__ out)
{
    __shared__ float part[3][64][33];   // waves 1..3 partials, pad 33: 25.3 KB

    const int g    = blockIdx.x;
    const int tid  = threadIdx.x;
    const int lane = tid & 63;
    const int wv   = tid >> 6;
    const int h    = lane & 31;
    const int dg   = lane >> 5;
    const int d0   = dg * 32;

    float wkr[32];
    #pragma unroll
    for (int j = 0; j < 32; ++j) wkr[j] = Wk[(d0 + j) * H + h];
    const float bkv = bk[h];

    const int s   = bounds[g];
    const int e   = bounds[g + 1];
    const int nA  = e - s;
    const int per = (nA + 3) >> 2;
    int a         = s + wv * per;
    const int ae  = min(a + per, e);

    float acc[32];
    #pragma unroll
    for (int j = 0; j < 32; ++j) acc[j] = 0.f;
    float es = 0.f;

    float4 A0, A1, A2, A3, A4, A5, A6, A7;
    float4 B0, B1, B2, B3, B4, B5, B6, B7;

#define LOAD8(R0, R1, R2, R3, R4, R5, R6, R7, aa)                              \
    {                                                                          \
        const float4* fp = (const float4*)(atom_feas + (size_t)(aa) * D + d0); \
        R0 = fp[0]; R1 = fp[1]; R2 = fp[2]; R3 = fp[3];                        \
        R4 = fp[4]; R5 = fp[5]; R6 = fp[6]; R7 = fp[7];                        \
    }

#define COMPUTE(R0, R1, R2, R3, R4, R5, R6, R7)                                \
    {                                                                          \
        float q0 = R0.x * wkr[0]  + R0.y * wkr[1]                              \
                 + R0.z * wkr[2]  + R0.w * wkr[3]                              \
                 + R1.x * wkr[4]  + R1.y * wkr[5]                              \
                 + R1.z * wkr[6]  + R1.w * wkr[7];                             \
        float q1 = R2.x * wkr[8]  + R2.y * wkr[9]                              \
                 + R2.z * wkr[10] + R2.w * wkr[11]                             \
                 + R3.x * wkr[12] + R3.y * wkr[13]                             \
                 + R3.z * wkr[14] + R3.w * wkr[15];                            \
        float q2 = R4.x * wkr[16] + R4.y * wkr[17]                             \
                 + R4.z * wkr[18] + R4.w * wkr[19]                             \
                 + R5.x * wkr[20] + R5.y * wkr[21]                             \
                 + R5.z * wkr[22] + R5.w * wkr[23];                            \
        float q3 = R6.x * wkr[24] + R6.y * wkr[25]                             \
                 + R6.z * wkr[26] + R6.w * wkr[27]                             \
                 + R7.x * wkr[28] + R7.y * wkr[29]                             \
                 + R7.z * wkr[30] + R7.w * wkr[31];                            \
        float wlog = (q0 + q1) + (q2 + q3);                                    \
        wlog += __shfl_xor(wlog, 32, 64);                                      \
        const float p = __expf(wlog + bkv);                                    \
        es += p;                                                               \
        acc[0]  += R0.x * p; acc[1]  += R0.y * p;                              \
        acc[2]  += R0.z * p; acc[3]  += R0.w * p;                              \
        acc[4]  += R1.x * p; acc[5]  += R1.y * p;                              \
        acc[6]  += R1.z * p; acc[7]  += R1.w * p;                              \
        acc[8]  += R2.x * p; acc[9]  += R2.y * p;                              \
        acc[10] += R2.z * p; acc[11] += R2.w * p;                              \
        acc[12] += R3.x * p; acc[13] += R3.y * p;                              \
        acc[14] += R3.z * p; acc[15] += R3.w * p;                              \
        acc[16] += R4.x * p; acc[17] += R4.y * p;                              \
        acc[18] += R4.z * p; acc[19] += R4.w * p;                              \
        acc[20] += R5.x * p; acc[21] += R5.y * p;                              \
        acc[22] += R5.z * p; acc[23] += R5.w * p;                              \
        acc[24] += R6.x * p; acc[25] += R6.y * p;                              \
        acc[26] += R6.z * p; acc[27] += R6.w * p;                              \
        acc[28] += R7.x * p; acc[29] += R7.y * p;                              \
        acc[30] += R7.z * p; acc[31] += R7.w * p;                              \
    }

    if (a < ae) {
        LOAD8(A0, A1, A2, A3, A4, A5, A6, A7, a);
        for (;;) {
            const int n1 = a + 1;
            if (n1 >= ae) { COMPUTE(A0, A1, A2, A3, A4, A5, A6, A7); break; }
            LOAD8(B0, B1, B2, B3, B4, B5, B6, B7, n1);
            COMPUTE(A0, A1, A2, A3, A4, A5, A6, A7);
            const int n2 = n1 + 1;
            if (n2 >= ae) { COMPUTE(B0, B1, B2, B3, B4, B5, B6, B7); break; }
            LOAD8(A0, A1, A2, A3, A4, A5, A6, A7, n2);
            COMPUTE(B0, B1, B2, B3, B4, B5, B6, B7);
            a = n2;
        }
    }
#undef LOAD8
#undef COMPUTE

    // ---- cross-wave combine (once per block)
    if (wv > 0) {
        #pragma unroll
        for (int j = 0; j < 32; ++j) part[wv - 1][lane][j] = acc[j];
        part[wv - 1][lane][32] = es;
    }
    __syncthreads();
    if (wv == 0) {
        #pragma unroll
        for (int j = 0; j < 32; ++j)
            acc[j] += part[0][lane][j] + part[1][lane][j] + part[2][lane][j];
        es += part[0][lane][32] + part[1][lane][32] + part[2][lane][32];
        const float inv = (es > 0.f) ? 1.0f / es : 0.f;
        float* og = out + (size_t)g * (D * H);
        #pragma unroll
        for (int j = 0; j < 32; ++j)
            og[(d0 + j) * H + h] = acc[j] * inv;   // 2x128B per instr, coalesced
    }
}

// ---------------- Fallback (ws too small): known-good fused kernel --------
#define CHUNK 64
__global__ __launch_bounds__(256) void fused_kernel(
    const float* __restrict__ atom_feas,
    const float* __restrict__ Wk,
    const float* __restrict__ bk,
    const int* __restrict__ owner,
    float* __restrict__ out,
    int n_atoms)
{
    __shared__ float fea_lds[CHUNK * D];
    __shared__ float w_lds[CHUNK * H];
    __shared__ float wk_lds[D * H];
    __shared__ float bk_lds[H];

    const int g   = blockIdx.x;
    const int tid = threadIdx.x;
    const int h   = tid & 31;
    const int grp = tid >> 5;

    for (int i = tid; i < D * H; i += 256) wk_lds[i] = Wk[i];
    if (tid < H) bk_lds[tid] = bk[tid];

    int lo = 0, hi = n_atoms;
    while (lo < hi) { int mid = (lo + hi) >> 1; if (owner[mid] < g) lo = mid + 1; else hi = mid; }
    const int seg_start = lo;
    hi = n_atoms;
    while (lo < hi) { int mid = (lo + hi) >> 1; if (owner[mid] < g + 1) lo = mid + 1; else hi = mid; }
    const int seg_end = lo;

    float acc[8];
    #pragma unroll
    for (int j = 0; j < 8; ++j) acc[j] = 0.f;
    float ps = 0.f;

    __syncthreads();

    for (int base = seg_start; base < seg_end; base += CHUNK) {
        const int na = min(CHUNK, seg_end - base);
        {
            const int nf4 = na * (D / 4);
            const float4* src = (const float4*)(atom_feas + (size_t)base * D);
            float4* dst = (float4*)fea_lds;
            for (int i = tid; i < nf4; i += 256) dst[i] = src[i];
        }
        __syncthreads();

        for (int pi = tid; pi < na * H; pi += 256) {
            const int aa = pi >> 5;
            const int hh = pi & 31;
            const float* fr = fea_lds + aa * D;
            float wvl = bk_lds[hh];
            #pragma unroll
            for (int k = 0; k < D; k += 4) {
                float4 f = *(const float4*)(fr + k);
                wvl += f.x * wk_lds[(k + 0) * H + hh];
                wvl += f.y * wk_lds[(k + 1) * H + hh];
                wvl += f.z * wk_lds[(k + 2) * H + hh];
                wvl += f.w * wk_lds[(k + 3) * H + hh];
            }
            w_lds[pi] = __expf(wvl);
        }
        __syncthreads();

        for (int aa = 0; aa < na; ++aa) {
            const float p = w_lds[aa * H + h];
            ps += p;
            const float* f = fea_lds + aa * D + grp * 8;
            #pragma unroll
            for (int j = 0; j < 8; ++j) acc[j] += f[j] * p;
        }
        __syncthreads();
    }

    const float inv = (ps > 0.f) ? 1.0f / ps : 0.f;
    float* og = out + (size_t)g * (D * H);
    #pragma unroll
    for (int j = 0; j < 8; ++j) og[(grp * 8 + j) * H + h] = acc[j] * inv;
}

extern "C" void kernel_launch(void* const* d_in, const int* in_sizes, int n_in,
                              void* d_out, int out_size, void* d_ws, size_t ws_size,
                              hipStream_t stream) {
    const float* atom_feas = (const float*)d_in[0];
    const float* Wk        = (const float*)d_in[1];
    const float* bk        = (const float*)d_in[2];
    // d_in[3] = atomic_numbers (unused by the reference)
    const int*   owner     = (const int*)d_in[4];
    const int n_atoms = in_sizes[4];
    float* out = (float*)d_out;

    if (ws_size >= (NC + 1) * sizeof(int)) {
        int* bounds = (int*)d_ws;
        bounds_kernel<<<(n_atoms + 255) / 256, 256, 0, stream>>>(owner, bounds, n_atoms);
        crystal_kernel<<<NC, 256, 0, stream>>>(atom_feas, Wk, bk, bounds, out);
    } else {
        fused_kernel<<<NC, 256, 0, stream>>>(atom_feas, Wk, bk, owner, out, n_atoms);
    }
}

// Round 9
// 47.566 us; speedup vs baseline: 1.8786x; 1.8617x over previous
//
#include <hip/hip_runtime.h>

#define NC 2048
#define D 64
#define H 32

// ---------------- K1: segment bounds (owner sorted ascending) -------------
__global__ void bounds_kernel(const int* __restrict__ owner,
                              int* __restrict__ bounds, int n) {
    int i = blockIdx.x * blockDim.x + threadIdx.x;
    if (i >= n) return;
    int o  = owner[i];
    int op = (i == 0) ? -1 : owner[i - 1];
    for (int g = op + 1; g <= o; ++g) bounds[g] = i;
    if (i == n - 1)
        for (int g = o + 1; g <= NC; ++g) bounds[g] = n;
}

// ---------------- K2: fully-fused per-crystal kernel ----------------------
// Block = 1 crystal, 256 threads = 4 waves; wave wv owns a CONTIGUOUS slice.
// Lane = (dg = lane>>5, h = lane&31):
//   wkr[32] = Wk[dg*32 .. +31][h]   (constant over atoms, registers)
//   acc[32] = out[g][dg*32+j][h]
// Per atom: 8 float4 fea loads -> 4 independent logit chains -> shfl_xor(32)
// cross-half reduce -> exp -> outer-product FMAs. Per-lane running sum of p
// IS the softmax denominator (no reductions). No max subtraction (softmax
// shift-invariance; |w| <~ 6, f32-safe; absmax 0.0078 vs thr 0.0478 R2-R8).
//
// R4-R8 lesson: the VGPR budget is derived from the LDS-implied occupancy.
// LDS 25.6KB -> 6 blocks/CU -> 6 waves/EU -> cap 512/6=85 -> ~11 floats/lane
// spilled to scratch (WRITE_SIZE +24MB, 90us). amdgpu_waves_per_eu(3,3) was
// IGNORED (R8 null). So pull the lever the allocator does respect: pad LDS
// to 42KB -> 3 blocks/CU -> 3 waves/EU -> cap 512/3=170 >= demand ~150
// -> no spill. 12 waves/CU remains enough with 2-deep prefetch + ILP.
__global__ __launch_bounds__(256)
void crystal_kernel(
    const float* __restrict__ atom_feas,
    const float* __restrict__ Wk,
    const float* __restrict__ bk,
    const int* __restrict__ bounds,
    float* __restrict__ out)
{
    __shared__ float part[3][64][56];   // 42KB: occupancy limiter (see above);
                                        // only [..][..][0..32] actually used

    const int g    = blockIdx.x;
    const int tid  = threadIdx.x;
    const int lane = tid & 63;
    const int wv   = tid >> 6;
    const int h    = lane & 31;
    const int dg   = lane >> 5;
    const int d0   = dg * 32;

    float wkr[32];
    #pragma unroll
    for (int j = 0; j < 32; ++j) wkr[j] = Wk[(d0 + j) * H + h];
    const float bkv = bk[h];

    const int s   = bounds[g];
    const int e   = bounds[g + 1];
    const int nA  = e - s;
    const int per = (nA + 3) >> 2;
    int a         = s + wv * per;
    const int ae  = min(a + per, e);

    float acc[32];
    #pragma unroll
    for (int j = 0; j < 32; ++j) acc[j] = 0.f;
    float es = 0.f;

    float4 A0, A1, A2, A3, A4, A5, A6, A7;
    float4 B0, B1, B2, B3, B4, B5, B6, B7;

#define LOAD8(R0, R1, R2, R3, R4, R5, R6, R7, aa)                              \
    {                                                                          \
        const float4* fp = (const float4*)(atom_feas + (size_t)(aa) * D + d0); \
        R0 = fp[0]; R1 = fp[1]; R2 = fp[2]; R3 = fp[3];                        \
        R4 = fp[4]; R5 = fp[5]; R6 = fp[6]; R7 = fp[7];                        \
    }

#define COMPUTE(R0, R1, R2, R3, R4, R5, R6, R7)                                \
    {                                                                          \
        float q0 = R0.x * wkr[0]  + R0.y * wkr[1]                              \
                 + R0.z * wkr[2]  + R0.w * wkr[3]                              \
                 + R1.x * wkr[4]  + R1.y * wkr[5]                              \
                 + R1.z * wkr[6]  + R1.w * wkr[7];                             \
        float q1 = R2.x * wkr[8]  + R2.y * wkr[9]                              \
                 + R2.z * wkr[10] + R2.w * wkr[11]                             \
                 + R3.x * wkr[12] + R3.y * wkr[13]                             \
                 + R3.z * wkr[14] + R3.w * wkr[15];                            \
        float q2 = R4.x * wkr[16] + R4.y * wkr[17]                             \
                 + R4.z * wkr[18] + R4.w * wkr[19]                             \
                 + R5.x * wkr[20] + R5.y * wkr[21]                             \
                 + R5.z * wkr[22] + R5.w * wkr[23];                            \
        float q3 = R6.x * wkr[24] + R6.y * wkr[25]                             \
                 + R6.z * wkr[26] + R6.w * wkr[27]                             \
                 + R7.x * wkr[28] + R7.y * wkr[29]                             \
                 + R7.z * wkr[30] + R7.w * wkr[31];                            \
        float wlog = (q0 + q1) + (q2 + q3);                                    \
        wlog += __shfl_xor(wlog, 32, 64);                                      \
        const float p = __expf(wlog + bkv);                                    \
        es += p;                                                               \
        acc[0]  += R0.x * p; acc[1]  += R0.y * p;                              \
        acc[2]  += R0.z * p; acc[3]  += R0.w * p;                              \
        acc[4]  += R1.x * p; acc[5]  += R1.y * p;                              \
        acc[6]  += R1.z * p; acc[7]  += R1.w * p;                              \
        acc[8]  += R2.x * p; acc[9]  += R2.y * p;                              \
        acc[10] += R2.z * p; acc[11] += R2.w * p;                              \
        acc[12] += R3.x * p; acc[13] += R3.y * p;                              \
        acc[14] += R3.z * p; acc[15] += R3.w * p;                              \
        acc[16] += R4.x * p; acc[17] += R4.y * p;                              \
        acc[18] += R4.z * p; acc[19] += R4.w * p;                              \
        acc[20] += R5.x * p; acc[21] += R5.y * p;                              \
        acc[22] += R5.z * p; acc[23] += R5.w * p;                              \
        acc[24] += R6.x * p; acc[25] += R6.y * p;                              \
        acc[26] += R6.z * p; acc[27] += R6.w * p;                              \
        acc[28] += R7.x * p; acc[29] += R7.y * p;                              \
        acc[30] += R7.z * p; acc[31] += R7.w * p;                              \
    }

    if (a < ae) {
        LOAD8(A0, A1, A2, A3, A4, A5, A6, A7, a);
        for (;;) {
            const int n1 = a + 1;
            if (n1 >= ae) { COMPUTE(A0, A1, A2, A3, A4, A5, A6, A7); break; }
            LOAD8(B0, B1, B2, B3, B4, B5, B6, B7, n1);
            COMPUTE(A0, A1, A2, A3, A4, A5, A6, A7);
            const int n2 = n1 + 1;
            if (n2 >= ae) { COMPUTE(B0, B1, B2, B3, B4, B5, B6, B7); break; }
            LOAD8(A0, A1, A2, A3, A4, A5, A6, A7, n2);
            COMPUTE(B0, B1, B2, B3, B4, B5, B6, B7);
            a = n2;
        }
    }
#undef LOAD8
#undef COMPUTE

    // ---- cross-wave combine (once per block)
    if (wv > 0) {
        #pragma unroll
        for (int j = 0; j < 32; ++j) part[wv - 1][lane][j] = acc[j];
        part[wv - 1][lane][32] = es;
    }
    __syncthreads();
    if (wv == 0) {
        #pragma unroll
        for (int j = 0; j < 32; ++j)
            acc[j] += part[0][lane][j] + part[1][lane][j] + part[2][lane][j];
        es += part[0][lane][32] + part[1][lane][32] + part[2][lane][32];
        const float inv = (es > 0.f) ? 1.0f / es : 0.f;
        float* og = out + (size_t)g * (D * H);
        #pragma unroll
        for (int j = 0; j < 32; ++j)
            og[(d0 + j) * H + h] = acc[j] * inv;   // 2x128B per instr, coalesced
    }
}

// ---------------- Fallback (ws too small): known-good fused kernel --------
#define CHUNK 64
__global__ __launch_bounds__(256) void fused_kernel(
    const float* __restrict__ atom_feas,
    const float* __restrict__ Wk,
    const float* __restrict__ bk,
    const int* __restrict__ owner,
    float* __restrict__ out,
    int n_atoms)
{
    __shared__ float fea_lds[CHUNK * D];
    __shared__ float w_lds[CHUNK * H];
    __shared__ float wk_lds[D * H];
    __shared__ float bk_lds[H];

    const int g   = blockIdx.x;
    const int tid = threadIdx.x;
    const int h   = tid & 31;
    const int grp = tid >> 5;

    for (int i = tid; i < D * H; i += 256) wk_lds[i] = Wk[i];
    if (tid < H) bk_lds[tid] = bk[tid];

    int lo = 0, hi = n_atoms;
    while (lo < hi) { int mid = (lo + hi) >> 1; if (owner[mid] < g) lo = mid + 1; else hi = mid; }
    const int seg_start = lo;
    hi = n_atoms;
    while (lo < hi) { int mid = (lo + hi) >> 1; if (owner[mid] < g + 1) lo = mid + 1; else hi = mid; }
    const int seg_end = lo;

    float acc[8];
    #pragma unroll
    for (int j = 0; j < 8; ++j) acc[j] = 0.f;
    float ps = 0.f;

    __syncthreads();

    for (int base = seg_start; base < seg_end; base += CHUNK) {
        const int na = min(CHUNK, seg_end - base);
        {
            const int nf4 = na * (D / 4);
            const float4* src = (const float4*)(atom_feas + (size_t)base * D);
            float4* dst = (float4*)fea_lds;
            for (int i = tid; i < nf4; i += 256) dst[i] = src[i];
        }
        __syncthreads();

        for (int pi = tid; pi < na * H; pi += 256) {
            const int aa = pi >> 5;
            const int hh = pi & 31;
            const float* fr = fea_lds + aa * D;
            float wvl = bk_lds[hh];
            #pragma unroll
            for (int k = 0; k < D; k += 4) {
                float4 f = *(const float4*)(fr + k);
                wvl += f.x * wk_lds[(k + 0) * H + hh];
                wvl += f.y * wk_lds[(k + 1) * H + hh];
                wvl += f.z * wk_lds[(k + 2) * H + hh];
                wvl += f.w * wk_lds[(k + 3) * H + hh];
            }
            w_lds[pi] = __expf(wvl);
        }
        __syncthreads();

        for (int aa = 0; aa < na; ++aa) {
            const float p = w_lds[aa * H + h];
            ps += p;
            const float* f = fea_lds + aa * D + grp * 8;
            #pragma unroll
            for (int j = 0; j < 8; ++j) acc[j] += f[j] * p;
        }
        __syncthreads();
    }

    const float inv = (ps > 0.f) ? 1.0f / ps : 0.f;
    float* og = out + (size_t)g * (D * H);
    #pragma unroll
    for (int j = 0; j < 8; ++j) og[(grp * 8 + j) * H + h] = acc[j] * inv;
}

extern "C" void kernel_launch(void* const* d_in, const int* in_sizes, int n_in,
                              void* d_out, int out_size, void* d_ws, size_t ws_size,
                              hipStream_t stream) {
    const float* atom_feas = (const float*)d_in[0];
    const float* Wk        = (const float*)d_in[1];
    const float* bk        = (const float*)d_in[2];
    // d_in[3] = atomic_numbers (unused by the reference)
    const int*   owner     = (const int*)d_in[4];
    const int n_atoms = in_sizes[4];
    float* out = (float*)d_out;

    if (ws_size >= (NC + 1) * sizeof(int)) {
        int* bounds = (int*)d_ws;
        bounds_kernel<<<(n_atoms + 255) / 256, 256, 0, stream>>>(owner, bounds, n_atoms);
        crystal_kernel<<<NC, 256, 0, stream>>>(atom_feas, Wk, bk, bounds, out);
    } else {
        fused_kernel<<<NC, 256, 0, stream>>>(atom_feas, Wk, bk, owner, out, n_atoms);
    }
}

// Round 10
// 36.688 us; speedup vs baseline: 2.4356x; 1.2965x over previous
//
#include <hip/hip_runtime.h>

#define NC 2048
#define D 64
#define H 32

// ---------------- K1: segment bounds (owner sorted ascending) -------------
__global__ void bounds_kernel(const int* __restrict__ owner,
                              int* __restrict__ bounds, int n) {
    int i = blockIdx.x * blockDim.x + threadIdx.x;
    if (i >= n) return;
    int o  = owner[i];
    int op = (i == 0) ? -1 : owner[i - 1];
    for (int g = op + 1; g <= o; ++g) bounds[g] = i;
    if (i == n - 1)
        for (int g = o + 1; g <= NC; ++g) bounds[g] = n;
}

// ---------------- K2: fused per-crystal kernel, LDS chunk staging ---------
// Block = 1 crystal, 4 waves; wave owns a contiguous atom slice, processed in
// 8-atom chunks staged through PER-WAVE LDS double buffers (no barriers):
//   chunk c+1: global->reg (2 float4/lane) issued BEFORE compute of chunk c,
//   reg->LDS ds_write at the top of iteration c+1. HBM latency (~300-900cy)
//   hides under ~1600cy of chunk compute (T14 async-stage, wave-private).
// Lane = (dg = lane>>5, h = lane&31): wkr[32] = Wk[dg*32..+31][h] in regs,
// acc[32] = out[g][dg*32+j][h]. Per atom: 8 ds_read_b128 (2-addr broadcast,
// conflict-free) -> 4-chain dot -> shfl_xor(32) -> exp -> 32 outer FMAs.
// Per-lane running sum of p IS the denominator. Tail atoms masked via p=0.
// No max subtraction (softmax shift-invariance, |w|<~6; absmax 0.0078 R2-R9).
//
// Occupancy law (R4-R9): VGPR cap = 512/(LDS-implied waves/EU). LDS 41.7KB
// -> 3 blocks/CU -> 3 waves/EU -> cap 170 >= demand (~130) -> no spill.
// part pad [33] (NOT 56: 56%32=24 gave 762k conflicts in R9; 33 -> 2/bank).
__global__ __launch_bounds__(256)
void crystal_kernel(
    const float* __restrict__ atom_feas,
    const float* __restrict__ Wk,
    const float* __restrict__ bk,
    const int* __restrict__ bounds,
    float* __restrict__ out,
    int n)
{
    __shared__ float part[3][64][33];       // 25.3 KB, conflict-free pad
    __shared__ float4 stage[4][2][128];     // 4 waves x 2 bufs x 2KB = 16 KB

    const int g    = blockIdx.x;
    const int tid  = threadIdx.x;
    const int lane = tid & 63;
    const int wv   = tid >> 6;
    const int h    = lane & 31;
    const int dg   = lane >> 5;
    const int d0   = dg * 32;

    float wkr[32];
    #pragma unroll
    for (int j = 0; j < 32; ++j) wkr[j] = Wk[(d0 + j) * H + h];
    const float bkv = bk[h];

    const int s   = bounds[g];
    const int e   = bounds[g + 1];
    const int per = (e - s + 3) >> 2;
    const int a0  = s + wv * per;
    const int ae  = min(a0 + per, e);

    float acc[32];
    #pragma unroll
    for (int j = 0; j < 32; ++j) acc[j] = 0.f;
    float es = 0.f;

    if (a0 < ae) {
        const int nchunk = (ae - a0 + 7) >> 3;
        const int maxf4  = n * 16 - 1;          // clamp staging reads in-bounds
        const float4* af4 = (const float4*)atom_feas;

        // prologue: load chunk 0 into staging regs
        int cb = a0;
        float4 r0 = af4[min(cb * 16 + lane,      maxf4)];
        float4 r1 = af4[min(cb * 16 + lane + 64, maxf4)];

        for (int c = 0; c < nchunk; ++c) {
            float4* sb = stage[wv][c & 1];
            sb[lane]      = r0;                  // ds_write chunk c
            sb[lane + 64] = r1;
            const int nb = cb + 8;
            if (c + 1 < nchunk) {                // issue chunk c+1 loads NOW;
                r0 = af4[min(nb * 16 + lane,      maxf4)];   // they fly during
                r1 = af4[min(nb * 16 + lane + 64, maxf4)];   // the compute below
            }

            #pragma unroll 2
            for (int i = 0; i < 8; ++i) {
                const int aa = cb + i;
                const float4* fp = sb + i * 16 + dg * 8;
                const float4 v0 = fp[0], v1 = fp[1], v2 = fp[2], v3 = fp[3];
                const float4 v4 = fp[4], v5 = fp[5], v6 = fp[6], v7 = fp[7];

                float q0 = v0.x * wkr[0]  + v0.y * wkr[1]
                         + v0.z * wkr[2]  + v0.w * wkr[3]
                         + v1.x * wkr[4]  + v1.y * wkr[5]
                         + v1.z * wkr[6]  + v1.w * wkr[7];
                float q1 = v2.x * wkr[8]  + v2.y * wkr[9]
                         + v2.z * wkr[10] + v2.w * wkr[11]
                         + v3.x * wkr[12] + v3.y * wkr[13]
                         + v3.z * wkr[14] + v3.w * wkr[15];
                float q2 = v4.x * wkr[16] + v4.y * wkr[17]
                         + v4.z * wkr[18] + v4.w * wkr[19]
                         + v5.x * wkr[20] + v5.y * wkr[21]
                         + v5.z * wkr[22] + v5.w * wkr[23];
                float q3 = v6.x * wkr[24] + v6.y * wkr[25]
                         + v6.z * wkr[26] + v6.w * wkr[27]
                         + v7.x * wkr[28] + v7.y * wkr[29]
                         + v7.z * wkr[30] + v7.w * wkr[31];
                float wl = (q0 + q1) + (q2 + q3);
                wl += __shfl_xor(wl, 32, 64);
                const float p = (aa < ae) ? __expf(wl + bkv) : 0.f;
                es += p;

                acc[0]  += v0.x * p; acc[1]  += v0.y * p;
                acc[2]  += v0.z * p; acc[3]  += v0.w * p;
                acc[4]  += v1.x * p; acc[5]  += v1.y * p;
                acc[6]  += v1.z * p; acc[7]  += v1.w * p;
                acc[8]  += v2.x * p; acc[9]  += v2.y * p;
                acc[10] += v2.z * p; acc[11] += v2.w * p;
                acc[12] += v3.x * p; acc[13] += v3.y * p;
                acc[14] += v3.z * p; acc[15] += v3.w * p;
                acc[16] += v4.x * p; acc[17] += v4.y * p;
                acc[18] += v4.z * p; acc[19] += v4.w * p;
                acc[20] += v5.x * p; acc[21] += v5.y * p;
                acc[22] += v5.z * p; acc[23] += v5.w * p;
                acc[24] += v6.x * p; acc[25] += v6.y * p;
                acc[26] += v6.z * p; acc[27] += v6.w * p;
                acc[28] += v7.x * p; acc[29] += v7.y * p;
                acc[30] += v7.z * p; acc[31] += v7.w * p;
            }
            cb = nb;
        }
    }

    // ---- cross-wave combine (once per block)
    if (wv > 0) {
        #pragma unroll
        for (int j = 0; j < 32; ++j) part[wv - 1][lane][j] = acc[j];
        part[wv - 1][lane][32] = es;
    }
    __syncthreads();
    if (wv == 0) {
        #pragma unroll
        for (int j = 0; j < 32; ++j)
            acc[j] += part[0][lane][j] + part[1][lane][j] + part[2][lane][j];
        es += part[0][lane][32] + part[1][lane][32] + part[2][lane][32];
        const float inv = (es > 0.f) ? 1.0f / es : 0.f;
        float* og = out + (size_t)g * (D * H);
        #pragma unroll
        for (int j = 0; j < 32; ++j)
            og[(d0 + j) * H + h] = acc[j] * inv;   // 2x128B per instr, coalesced
    }
}

// ---------------- Fallback (ws too small): known-good fused kernel --------
#define CHUNK 64
__global__ __launch_bounds__(256) void fused_kernel(
    const float* __restrict__ atom_feas,
    const float* __restrict__ Wk,
    const float* __restrict__ bk,
    const int* __restrict__ owner,
    float* __restrict__ out,
    int n_atoms)
{
    __shared__ float fea_lds[CHUNK * D];
    __shared__ float w_lds[CHUNK * H];
    __shared__ float wk_lds[D * H];
    __shared__ float bk_lds[H];

    const int g   = blockIdx.x;
    const int tid = threadIdx.x;
    const int h   = tid & 31;
    const int grp = tid >> 5;

    for (int i = tid; i < D * H; i += 256) wk_lds[i] = Wk[i];
    if (tid < H) bk_lds[tid] = bk[tid];

    int lo = 0, hi = n_atoms;
    while (lo < hi) { int mid = (lo + hi) >> 1; if (owner[mid] < g) lo = mid + 1; else hi = mid; }
    const int seg_start = lo;
    hi = n_atoms;
    while (lo < hi) { int mid = (lo + hi) >> 1; if (owner[mid] < g + 1) lo = mid + 1; else hi = mid; }
    const int seg_end = lo;

    float acc[8];
    #pragma unroll
    for (int j = 0; j < 8; ++j) acc[j] = 0.f;
    float ps = 0.f;

    __syncthreads();

    for (int base = seg_start; base < seg_end; base += CHUNK) {
        const int na = min(CHUNK, seg_end - base);
        {
            const int nf4 = na * (D / 4);
            const float4* src = (const float4*)(atom_feas + (size_t)base * D);
            float4* dst = (float4*)fea_lds;
            for (int i = tid; i < nf4; i += 256) dst[i] = src[i];
        }
        __syncthreads();

        for (int pi = tid; pi < na * H; pi += 256) {
            const int aa = pi >> 5;
            const int hh = pi & 31;
            const float* fr = fea_lds + aa * D;
            float wvl = bk_lds[hh];
            #pragma unroll
            for (int k = 0; k < D; k += 4) {
                float4 f = *(const float4*)(fr + k);
                wvl += f.x * wk_lds[(k + 0) * H + hh];
                wvl += f.y * wk_lds[(k + 1) * H + hh];
                wvl += f.z * wk_lds[(k + 2) * H + hh];
                wvl += f.w * wk_lds[(k + 3) * H + hh];
            }
            w_lds[pi] = __expf(wvl);
        }
        __syncthreads();

        for (int aa = 0; aa < na; ++aa) {
            const float p = w_lds[aa * H + h];
            ps += p;
            const float* f = fea_lds + aa * D + grp * 8;
            #pragma unroll
            for (int j = 0; j < 8; ++j) acc[j] += f[j] * p;
        }
        __syncthreads();
    }

    const float inv = (ps > 0.f) ? 1.0f / ps : 0.f;
    float* og = out + (size_t)g * (D * H);
    #pragma unroll
    for (int j = 0; j < 8; ++j) og[(grp * 8 + j) * H + h] = acc[j] * inv;
}

extern "C" void kernel_launch(void* const* d_in, const int* in_sizes, int n_in,
                              void* d_out, int out_size, void* d_ws, size_t ws_size,
                              hipStream_t stream) {
    const float* atom_feas = (const float*)d_in[0];
    const float* Wk        = (const float*)d_in[1];
    const float* bk        = (const float*)d_in[2];
    // d_in[3] = atomic_numbers (unused by the reference)
    const int*   owner     = (const int*)d_in[4];
    const int n_atoms = in_sizes[4];
    float* out = (float*)d_out;

    if (ws_size >= (NC + 1) * sizeof(int)) {
        int* bounds = (int*)d_ws;
        bounds_kernel<<<(n_atoms + 255) / 256, 256, 0, stream>>>(owner, bounds, n_atoms);
        crystal_kernel<<<NC, 256, 0, stream>>>(atom_feas, Wk, bk, bounds, out, n_atoms);
    } else {
        fused_kernel<<<NC, 256, 0, stream>>>(atom_feas, Wk, bk, owner, out, n_atoms);
    }
}

// Round 12
// 35.880 us; speedup vs baseline: 2.4904x; 1.0225x over previous
//
#include <hip/hip_runtime.h>

#define NC 2048
#define D 64
#define H 32

typedef __fp16 h2 __attribute__((ext_vector_type(2)));
typedef unsigned int u32;

#if __has_builtin(__builtin_amdgcn_fdot2)
#define FDOT2(a, b, c) __builtin_amdgcn_fdot2((a), (b), (c), false)
#else
#define FDOT2(a, b, c) ((c) + (float)(a)[0] * (float)(b)[0] + (float)(a)[1] * (float)(b)[1])
#endif
#define BC2(u) __builtin_bit_cast(h2, (u))

// ---------------- K1: segment bounds (owner sorted ascending) -------------
__global__ void bounds_kernel(const int* __restrict__ owner,
                              int* __restrict__ bounds, int n) {
    int i = blockIdx.x * blockDim.x + threadIdx.x;
    if (i >= n) return;
    int o  = owner[i];
    int op = (i == 0) ? -1 : owner[i - 1];
    for (int g = op + 1; g <= o; ++g) bounds[g] = i;
    if (i == n - 1)
        for (int g = o + 1; g <= NC; ++g) bounds[g] = n;
}

// ---------------- K2: fused per-crystal kernel, FP16 LDS chunk staging ----
// R10 post-mortem: DS-pipe-bound (8 ds_read_b128/atom/wave ~96cy on the
// CU-shared LDS pipe vs ~140 VALU cy over 4 SIMDs). Fix: stage fea as PACKED
// FP16 (128B/atom) -> 4 ds_read_b128/atom/wave; dot consumes half2 via
// v_dot2_f32_f16 (2 MAC/instr, no unpack); outer product unpacks via
// (float)h2[i] (v_fma_mix-able). fp16 err ~5e-4 -> out err ~0.003 << 0.0478.
// Per-wave private double-buffered staging (no barriers in loop): global->reg
// prefetch 1 chunk (8 atoms) ahead; reg->(pack)->LDS at loop top.
// Occupancy law (R4-R9): VGPR cap = 512/(LDS-implied waves/EU).
// LDS 33.5KB -> 4 blocks/CU -> cap 128 >= demand ~110 -> no spill,
// 16 waves/CU. part pad [33] = conflict-free (R9's [56] was 8-way).
__global__ __launch_bounds__(256)
void crystal_kernel(
    const float* __restrict__ atom_feas,
    const float* __restrict__ Wk,
    const float* __restrict__ bk,
    const int* __restrict__ bounds,
    float* __restrict__ out,
    int n)
{
    __shared__ float part[3][64][33];                  // 25.3 KB
    __shared__ __align__(16) u32 stage[4][2][8][32];   // 8 KB (atom row = 128B fp16)

    const int g    = blockIdx.x;
    const int tid  = threadIdx.x;
    const int lane = tid & 63;
    const int wv   = tid >> 6;
    const int h    = lane & 31;
    const int dg   = lane >> 5;
    const int d0   = dg * 32;

    // Wk column slice as packed half2 (16 regs); coalesced f32 loads
    h2 wkh[16];
    #pragma unroll
    for (int j = 0; j < 16; ++j) {
        const float wa = Wk[(d0 + 2 * j) * H + h];
        const float wb = Wk[(d0 + 2 * j + 1) * H + h];
        wkh[j] = __builtin_amdgcn_cvt_pkrtz(wa, wb);
    }
    const float bkv = bk[h];

    const int s   = bounds[g];
    const int e   = bounds[g + 1];
    const int per = (e - s + 3) >> 2;
    const int a0  = s + wv * per;
    const int ae  = min(a0 + per, e);

    float acc[32];
    #pragma unroll
    for (int j = 0; j < 32; ++j) acc[j] = 0.f;
    float es = 0.f;

    if (a0 < ae) {
        const int nchunk = (ae - a0 + 7) >> 3;
        const int maxf4  = n * 16 - 1;           // clamp staging reads in-bounds
        const float4* af4 = (const float4*)atom_feas;

        int cb = a0;                              // prologue: chunk 0 -> regs
        float4 r0 = af4[min(cb * 16 + lane,      maxf4)];
        float4 r1 = af4[min(cb * 16 + lane + 64, maxf4)];

        for (int c = 0; c < nchunk; ++c) {
            {   // pack chunk c to fp16, write to wave-private LDS buffer
                uint2* sw = (uint2*)stage[wv][c & 1];
                const h2 p0 = __builtin_amdgcn_cvt_pkrtz(r0.x, r0.y);
                const h2 p1 = __builtin_amdgcn_cvt_pkrtz(r0.z, r0.w);
                const h2 p2 = __builtin_amdgcn_cvt_pkrtz(r1.x, r1.y);
                const h2 p3 = __builtin_amdgcn_cvt_pkrtz(r1.z, r1.w);
                uint2 w0, w1;
                w0.x = __builtin_bit_cast(u32, p0); w0.y = __builtin_bit_cast(u32, p1);
                w1.x = __builtin_bit_cast(u32, p2); w1.y = __builtin_bit_cast(u32, p3);
                const int slot = lane & 15, arow = lane >> 4;
                sw[arow * 16 + slot]       = w0;   // atoms 0..3 of chunk
                sw[(arow + 4) * 16 + slot] = w1;   // atoms 4..7
            }
            const int nb = cb + 8;
            if (c + 1 < nchunk) {                  // issue chunk c+1 loads now;
                r0 = af4[min(nb * 16 + lane,      maxf4)];  // fly during compute
                r1 = af4[min(nb * 16 + lane + 64, maxf4)];
            }

            const uint4* srbase = (const uint4*)stage[wv][c & 1];
            #pragma unroll 2
            for (int i = 0; i < 8; ++i) {
                const int aa = cb + i;
                const uint4* sr = srbase + i * 8 + dg * 4;   // 64B fp16 half-row
                const uint4 x0 = sr[0], x1 = sr[1], x2 = sr[2], x3 = sr[3];

                float q0 = 0.f, q1 = 0.f, q2 = 0.f, q3 = 0.f;
                q0 = FDOT2(BC2(x0.x), wkh[0],  q0);
                q0 = FDOT2(BC2(x0.y), wkh[1],  q0);
                q0 = FDOT2(BC2(x0.z), wkh[2],  q0);
                q0 = FDOT2(BC2(x0.w), wkh[3],  q0);
                q1 = FDOT2(BC2(x1.x), wkh[4],  q1);
                q1 = FDOT2(BC2(x1.y), wkh[5],  q1);
                q1 = FDOT2(BC2(x1.z), wkh[6],  q1);
                q1 = FDOT2(BC2(x1.w), wkh[7],  q1);
                q2 = FDOT2(BC2(x2.x), wkh[8],  q2);
                q2 = FDOT2(BC2(x2.y), wkh[9],  q2);
                q2 = FDOT2(BC2(x2.z), wkh[10], q2);
                q2 = FDOT2(BC2(x2.w), wkh[11], q2);
                q3 = FDOT2(BC2(x3.x), wkh[12], q3);
                q3 = FDOT2(BC2(x3.y), wkh[13], q3);
                q3 = FDOT2(BC2(x3.z), wkh[14], q3);
                q3 = FDOT2(BC2(x3.w), wkh[15], q3);
                float wl = (q0 + q1) + (q2 + q3);
                wl += __shfl_xor(wl, 32, 64);
                const float p = (aa < ae) ? __expf(wl + bkv) : 0.f;
                es += p;

#define OUT2(U, j) { const h2 hh = BC2(U); \
                     acc[j]     += (float)hh[0] * p; \
                     acc[(j)+1] += (float)hh[1] * p; }
                OUT2(x0.x, 0)  OUT2(x0.y, 2)  OUT2(x0.z, 4)  OUT2(x0.w, 6)
                OUT2(x1.x, 8)  OUT2(x1.y, 10) OUT2(x1.z, 12) OUT2(x1.w, 14)
                OUT2(x2.x, 16) OUT2(x2.y, 18) OUT2(x2.z, 20) OUT2(x2.w, 22)
                OUT2(x3.x, 24) OUT2(x3.y, 26) OUT2(x3.z, 28) OUT2(x3.w, 30)
#undef OUT2
            }
            cb = nb;
        }
    }

    // ---- cross-wave combine (once per block)
    if (wv > 0) {
        #pragma unroll
        for (int j = 0; j < 32; ++j) part[wv - 1][lane][j] = acc[j];
        part[wv - 1][lane][32] = es;
    }
    __syncthreads();
    if (wv == 0) {
        #pragma unroll
        for (int j = 0; j < 32; ++j)
            acc[j] += part[0][lane][j] + part[1][lane][j] + part[2][lane][j];
        es += part[0][lane][32] + part[1][lane][32] + part[2][lane][32];
        const float inv = (es > 0.f) ? 1.0f / es : 0.f;
        float* og = out + (size_t)g * (D * H);
        #pragma unroll
        for (int j = 0; j < 32; ++j)
            og[(d0 + j) * H + h] = acc[j] * inv;   // 2x128B per instr, coalesced
    }
}

// ---------------- Fallback (ws too small): known-good fused kernel --------
#define CHUNK 64
__global__ __launch_bounds__(256) void fused_kernel(
    const float* __restrict__ atom_feas,
    const float* __restrict__ Wk,
    const float* __restrict__ bk,
    const int* __restrict__ owner,
    float* __restrict__ out,
    int n_atoms)
{
    __shared__ float fea_lds[CHUNK * D];
    __shared__ float w_lds[CHUNK * H];
    __shared__ float wk_lds[D * H];
    __shared__ float bk_lds[H];

    const int g   = blockIdx.x;
    const int tid = threadIdx.x;
    const int h   = tid & 31;
    const int grp = tid >> 5;

    for (int i = tid; i < D * H; i += 256) wk_lds[i] = Wk[i];
    if (tid < H) bk_lds[tid] = bk[tid];

    int lo = 0, hi = n_atoms;
    while (lo < hi) { int mid = (lo + hi) >> 1; if (owner[mid] < g) lo = mid + 1; else hi = mid; }
    const int seg_start = lo;
    hi = n_atoms;
    while (lo < hi) { int mid = (lo + hi) >> 1; if (owner[mid] < g + 1) lo = mid + 1; else hi = mid; }
    const int seg_end = lo;

    float acc[8];
    #pragma unroll
    for (int j = 0; j < 8; ++j) acc[j] = 0.f;
    float ps = 0.f;

    __syncthreads();

    for (int base = seg_start; base < seg_end; base += CHUNK) {
        const int na = min(CHUNK, seg_end - base);
        {
            const int nf4 = na * (D / 4);
            const float4* src = (const float4*)(atom_feas + (size_t)base * D);
            float4* dst = (float4*)fea_lds;
            for (int i = tid; i < nf4; i += 256) dst[i] = src[i];
        }
        __syncthreads();

        for (int pi = tid; pi < na * H; pi += 256) {
            const int aa = pi >> 5;
            const int hh = pi & 31;
            const float* fr = fea_lds + aa * D;
            float wvl = bk_lds[hh];
            #pragma unroll
            for (int k = 0; k < D; k += 4) {
                float4 f = *(const float4*)(fr + k);
                wvl += f.x * wk_lds[(k + 0) * H + hh];
                wvl += f.y * wk_lds[(k + 1) * H + hh];
                wvl += f.z * wk_lds[(k + 2) * H + hh];
                wvl += f.w * wk_lds[(k + 3) * H + hh];
            }
            w_lds[pi] = __expf(wvl);
        }
        __syncthreads();

        for (int aa = 0; aa < na; ++aa) {
            const float p = w_lds[aa * H + h];
            ps += p;
            const float* f = fea_lds + aa * D + grp * 8;
            #pragma unroll
            for (int j = 0; j < 8; ++j) acc[j] += f[j] * p;
        }
        __syncthreads();
    }

    const float inv = (ps > 0.f) ? 1.0f / ps : 0.f;
    float* og = out + (size_t)g * (D * H);
    #pragma unroll
    for (int j = 0; j < 8; ++j) og[(grp * 8 + j) * H + h] = acc[j] * inv;
}

extern "C" void kernel_launch(void* const* d_in, const int* in_sizes, int n_in,
                              void* d_out, int out_size, void* d_ws, size_t ws_size,
                              hipStream_t stream) {
    const float* atom_feas = (const float*)d_in[0];
    const float* Wk        = (const float*)d_in[1];
    const float* bk        = (const float*)d_in[2];
    // d_in[3] = atomic_numbers (unused by the reference)
    const int*   owner     = (const int*)d_in[4];
    const int n_atoms = in_sizes[4];
    float* out = (float*)d_out;

    if (ws_size >= (NC + 1) * sizeof(int)) {
        int* bounds = (int*)d_ws;
        bounds_kernel<<<(n_atoms + 255) / 256, 256, 0, stream>>>(owner, bounds, n_atoms);
        crystal_kernel<<<NC, 256, 0, stream>>>(atom_feas, Wk, bk, bounds, out, n_atoms);
    } else {
        fused_kernel<<<NC, 256, 0, stream>>>(atom_feas, Wk, bk, owner, out, n_atoms);
    }
}

// Round 13
// 34.437 us; speedup vs baseline: 2.5948x; 1.0419x over previous
//
#include <hip/hip_runtime.h>

#define NC 2048
#define D 64
#define H 32

typedef __fp16 h2 __attribute__((ext_vector_type(2)));
typedef unsigned int u32;

#if __has_builtin(__builtin_amdgcn_fdot2)
#define FDOT2(a, b, c) __builtin_amdgcn_fdot2((a), (b), (c), false)
#else
#define FDOT2(a, b, c) ((c) + (float)(a)[0] * (float)(b)[0] + (float)(a)[1] * (float)(b)[1])
#endif
#define BC2(u) __builtin_bit_cast(h2, (u))

// ---------------- K1: segment bounds (owner sorted ascending) -------------
__global__ void bounds_kernel(const int* __restrict__ owner,
                              int* __restrict__ bounds, int n) {
    int i = blockIdx.x * blockDim.x + threadIdx.x;
    if (i >= n) return;
    int o  = owner[i];
    int op = (i == 0) ? -1 : owner[i - 1];
    for (int g = op + 1; g <= o; ++g) bounds[g] = i;
    if (i == n - 1)
        for (int g = o + 1; g <= NC; ++g) bounds[g] = n;
}

// ---------------- K2: per-crystal kernel, 2-wave blocks -------------------
// R12 post-mortem: compute loop fine but OccupancyPercent ~15% (R9) — 4-wave
// blocks with 4x-redundant state + 3-way combine drain unevenly; only ~3-4
// waves/SIMD to hide the per-atom chain (VALUBusy 35%). R13: SAME verified
// compute (fp16 LDS chunk staging, FDOT2 dot, shfl_xor cross-half, per-lane
// denominator), but 1 crystal per 128-THREAD block (2 waves): 2048 small
// blocks -> 8 blocks/CU, 16 waves/CU (4/SIMD), half the prologue redundancy,
// 1 barrier + 1 combine. LDS deliberately shaped to ~19.7KB so LDS-implied
// occupancy = 8 blocks/CU -> 4 waves/EU -> VGPR cap 512/4=128 >= demand ~110
// -> no spill (R4-R9 occupancy law used as a design tool).
__global__ __launch_bounds__(128)
void crystal_kernel(
    const float* __restrict__ atom_feas,
    const float* __restrict__ Wk,
    const float* __restrict__ bk,
    const int* __restrict__ bounds,
    float* __restrict__ out,
    int n)
{
    __shared__ float part[64][33];                     // 8.4 KB (wave1 partials)
    __shared__ __align__(16) u32 stage[2][2][8][32];   // 4 KB fp16 staging
    __shared__ float lds_pad[1800];                    // 7.2 KB occupancy shaper

    const int g    = blockIdx.x;
    const int tid  = threadIdx.x;
    const int lane = tid & 63;
    const int wv   = tid >> 6;          // 0 or 1
    const int h    = lane & 31;
    const int dg   = lane >> 5;
    const int d0   = dg * 32;

    // Wk column slice as packed half2 (16 regs); coalesced f32 loads
    h2 wkh[16];
    #pragma unroll
    for (int j = 0; j < 16; ++j) {
        const float wa = Wk[(d0 + 2 * j) * H + h];
        const float wb = Wk[(d0 + 2 * j + 1) * H + h];
        wkh[j] = __builtin_amdgcn_cvt_pkrtz(wa, wb);
    }
    const float bkv = bk[h];

    const int s   = bounds[g];
    const int e   = bounds[g + 1];
    const int per = (e - s + 1) >> 1;   // contiguous half per wave
    const int a0  = s + wv * per;
    const int ae  = min(a0 + per, e);

    float acc[32];
    #pragma unroll
    for (int j = 0; j < 32; ++j) acc[j] = 0.f;
    float es = 0.f;

    if (a0 < ae) {
        const int nchunk = (ae - a0 + 7) >> 3;
        const int maxf4  = n * 16 - 1;            // clamp staging reads in-bounds
        const float4* af4 = (const float4*)atom_feas;

        int cb = a0;                               // prologue: chunk 0 -> regs
        float4 r0 = af4[min(cb * 16 + lane,      maxf4)];
        float4 r1 = af4[min(cb * 16 + lane + 64, maxf4)];

        for (int c = 0; c < nchunk; ++c) {
            {   // pack chunk c to fp16, write to wave-private LDS buffer
                uint2* sw = (uint2*)stage[wv][c & 1];
                const h2 p0 = __builtin_amdgcn_cvt_pkrtz(r0.x, r0.y);
                const h2 p1 = __builtin_amdgcn_cvt_pkrtz(r0.z, r0.w);
                const h2 p2 = __builtin_amdgcn_cvt_pkrtz(r1.x, r1.y);
                const h2 p3 = __builtin_amdgcn_cvt_pkrtz(r1.z, r1.w);
                uint2 w0, w1;
                w0.x = __builtin_bit_cast(u32, p0); w0.y = __builtin_bit_cast(u32, p1);
                w1.x = __builtin_bit_cast(u32, p2); w1.y = __builtin_bit_cast(u32, p3);
                const int slot = lane & 15, arow = lane >> 4;
                sw[arow * 16 + slot]       = w0;   // atoms 0..3 of chunk
                sw[(arow + 4) * 16 + slot] = w1;   // atoms 4..7
            }
            const int nb = cb + 8;
            if (c + 1 < nchunk) {                  // issue chunk c+1 loads now;
                r0 = af4[min(nb * 16 + lane,      maxf4)];  // fly during compute
                r1 = af4[min(nb * 16 + lane + 64, maxf4)];
            }

            const uint4* srbase = (const uint4*)stage[wv][c & 1];
            #pragma unroll 2
            for (int i = 0; i < 8; ++i) {
                const int aa = cb + i;
                const uint4* sr = srbase + i * 8 + dg * 4;   // 64B fp16 half-row
                const uint4 x0 = sr[0], x1 = sr[1], x2 = sr[2], x3 = sr[3];

                float q0 = 0.f, q1 = 0.f, q2 = 0.f, q3 = 0.f;
                q0 = FDOT2(BC2(x0.x), wkh[0],  q0);
                q0 = FDOT2(BC2(x0.y), wkh[1],  q0);
                q0 = FDOT2(BC2(x0.z), wkh[2],  q0);
                q0 = FDOT2(BC2(x0.w), wkh[3],  q0);
                q1 = FDOT2(BC2(x1.x), wkh[4],  q1);
                q1 = FDOT2(BC2(x1.y), wkh[5],  q1);
                q1 = FDOT2(BC2(x1.z), wkh[6],  q1);
                q1 = FDOT2(BC2(x1.w), wkh[7],  q1);
                q2 = FDOT2(BC2(x2.x), wkh[8],  q2);
                q2 = FDOT2(BC2(x2.y), wkh[9],  q2);
                q2 = FDOT2(BC2(x2.z), wkh[10], q2);
                q2 = FDOT2(BC2(x2.w), wkh[11], q2);
                q3 = FDOT2(BC2(x3.x), wkh[12], q3);
                q3 = FDOT2(BC2(x3.y), wkh[13], q3);
                q3 = FDOT2(BC2(x3.z), wkh[14], q3);
                q3 = FDOT2(BC2(x3.w), wkh[15], q3);
                float wl = (q0 + q1) + (q2 + q3);
                wl += __shfl_xor(wl, 32, 64);
                const float p = (aa < ae) ? __expf(wl + bkv) : 0.f;
                es += p;

#define OUT2(U, j) { const h2 hh = BC2(U); \
                     acc[j]     += (float)hh[0] * p; \
                     acc[(j)+1] += (float)hh[1] * p; }
                OUT2(x0.x, 0)  OUT2(x0.y, 2)  OUT2(x0.z, 4)  OUT2(x0.w, 6)
                OUT2(x1.x, 8)  OUT2(x1.y, 10) OUT2(x1.z, 12) OUT2(x1.w, 14)
                OUT2(x2.x, 16) OUT2(x2.y, 18) OUT2(x2.z, 20) OUT2(x2.w, 22)
                OUT2(x3.x, 24) OUT2(x3.y, 26) OUT2(x3.z, 28) OUT2(x3.w, 30)
#undef OUT2
            }
            cb = nb;
        }
    }

    // keep lds_pad allocated (runtime-false condition the compiler can't fold)
    if (e < s) lds_pad[tid] = es;

    // ---- cross-wave combine (once per block)
    if (wv == 1) {
        #pragma unroll
        for (int j = 0; j < 32; ++j) part[lane][j] = acc[j];
        part[lane][32] = es;
    }
    __syncthreads();
    if (wv == 0) {
        #pragma unroll
        for (int j = 0; j < 32; ++j) acc[j] += part[lane][j];
        es += part[lane][32];
        const float inv = (es > 0.f) ? 1.0f / es : 0.f;
        float* og = out + (size_t)g * (D * H);
        #pragma unroll
        for (int j = 0; j < 32; ++j)
            og[(d0 + j) * H + h] = acc[j] * inv;   // 2x128B per instr, coalesced
    }
}

// ---------------- Fallback (ws too small): known-good fused kernel --------
#define CHUNK 64
__global__ __launch_bounds__(256) void fused_kernel(
    const float* __restrict__ atom_feas,
    const float* __restrict__ Wk,
    const float* __restrict__ bk,
    const int* __restrict__ owner,
    float* __restrict__ out,
    int n_atoms)
{
    __shared__ float fea_lds[CHUNK * D];
    __shared__ float w_lds[CHUNK * H];
    __shared__ float wk_lds[D * H];
    __shared__ float bk_lds[H];

    const int g   = blockIdx.x;
    const int tid = threadIdx.x;
    const int h   = tid & 31;
    const int grp = tid >> 5;

    for (int i = tid; i < D * H; i += 256) wk_lds[i] = Wk[i];
    if (tid < H) bk_lds[tid] = bk[tid];

    int lo = 0, hi = n_atoms;
    while (lo < hi) { int mid = (lo + hi) >> 1; if (owner[mid] < g) lo = mid + 1; else hi = mid; }
    const int seg_start = lo;
    hi = n_atoms;
    while (lo < hi) { int mid = (lo + hi) >> 1; if (owner[mid] < g + 1) lo = mid + 1; else hi = mid; }
    const int seg_end = lo;

    float acc[8];
    #pragma unroll
    for (int j = 0; j < 8; ++j) acc[j] = 0.f;
    float ps = 0.f;

    __syncthreads();

    for (int base = seg_start; base < seg_end; base += CHUNK) {
        const int na = min(CHUNK, seg_end - base);
        {
            const int nf4 = na * (D / 4);
            const float4* src = (const float4*)(atom_feas + (size_t)base * D);
            float4* dst = (float4*)fea_lds;
            for (int i = tid; i < nf4; i += 256) dst[i] = src[i];
        }
        __syncthreads();

        for (int pi = tid; pi < na * H; pi += 256) {
            const int aa = pi >> 5;
            const int hh = pi & 31;
            const float* fr = fea_lds + aa * D;
            float wvl = bk_lds[hh];
            #pragma unroll
            for (int k = 0; k < D; k += 4) {
                float4 f = *(const float4*)(fr + k);
                wvl += f.x * wk_lds[(k + 0) * H + hh];
                wvl += f.y * wk_lds[(k + 1) * H + hh];
                wvl += f.z * wk_lds[(k + 2) * H + hh];
                wvl += f.w * wk_lds[(k + 3) * H + hh];
            }
            w_lds[pi] = __expf(wvl);
        }
        __syncthreads();

        for (int aa = 0; aa < na; ++aa) {
            const float p = w_lds[aa * H + h];
            ps += p;
            const float* f = fea_lds + aa * D + grp * 8;
            #pragma unroll
            for (int j = 0; j < 8; ++j) acc[j] += f[j] * p;
        }
        __syncthreads();
    }

    const float inv = (ps > 0.f) ? 1.0f / ps : 0.f;
    float* og = out + (size_t)g * (D * H);
    #pragma unroll
    for (int j = 0; j < 8; ++j) og[(grp * 8 + j) * H + h] = acc[j] * inv;
}

extern "C" void kernel_launch(void* const* d_in, const int* in_sizes, int n_in,
                              void* d_out, int out_size, void* d_ws, size_t ws_size,
                              hipStream_t stream) {
    const float* atom_feas = (const float*)d_in[0];
    const float* Wk        = (const float*)d_in[1];
    const float* bk        = (const float*)d_in[2];
    // d_in[3] = atomic_numbers (unused by the reference)
    const int*   owner     = (const int*)d_in[4];
    const int n_atoms = in_sizes[4];
    float* out = (float*)d_out;

    if (ws_size >= (NC + 1) * sizeof(int)) {
        int* bounds = (int*)d_ws;
        bounds_kernel<<<(n_atoms + 255) / 256, 256, 0, stream>>>(owner, bounds, n_atoms);
        crystal_kernel<<<NC, 128, 0, stream>>>(atom_feas, Wk, bk, bounds, out, n_atoms);
    } else {
        fused_kernel<<<NC, 256, 0, stream>>>(atom_feas, Wk, bk, owner, out, n_atoms);
    }
}